// Round 19
// baseline (595.621 us; speedup 1.0000x reference)
//
#include <hip/hip_runtime.h>
#include <cstddef>

#define NB 32
#define NS 64
#define NH 768
#define NSEG_ (NB*NS)      // 2048
#define NIN 816
#define G4 3072
#define HOR_ 24
#define FBLK 192           // merged blocks: each owns 4 j of L0 + 4 j of L1
#define LTHR 512           // 8 waves/block

// MFMA fragment types (short-based bf16, compile-verified on gfx950)
typedef __attribute__((ext_vector_type(8))) short bf16x8;
typedef __attribute__((ext_vector_type(4))) float f32x4;
typedef __attribute__((ext_vector_type(8))) unsigned short u16x8;

// lstm dynamic-LDS: TWO bf16 h planes [32][776 u16] + partial-C [8][16][33]
#define HP2 776            // plane row stride in u16 (768 + 8 pad; 16B-aligned)
#define SMEM_BYTES (2*32*HP2*2 + 8*528*4)   // 99328 + 16896 = 116224

// workspace offsets (floats)
#define OFF_X      0
#define SZ_X       (NSEG_*NIN)
#define OFF_MEAN   (OFF_X + SZ_X)
#define SZ_MEAN    (NSEG_*NH)
#define OFF_TMP    (OFF_MEAN + SZ_MEAN)
#define OFF_H0PK   (OFF_TMP + SZ_MEAN)      // [2048][768] bf16 u16 (half used)
#define OFF_H1PK   (OFF_H0PK + SZ_MEAN)
#define OFF_XG     (OFF_H1PK + SZ_MEAN)
#define SZ_XG      (NSEG_*G4)
#define OFF_HZERO  (OFF_XG + SZ_XG)
#define SZ_HZERO   (NB*NH)
#define OFF_FLG    (OFF_HZERO + SZ_HZERO)   // 192 flag slots, 16B apart
// transient buffers (regions dead at time of use):
#define OFF_W1T    OFF_TMP                  // 768*768, dead after W12 GEMM
#define OFF_W12    (OFF_TMP + 620000)       // 768*768, dead after encoded GEMM
#define OFF_B12    (OFF_TMP + 1250000)      // 768, dead after encoded GEMM
#define OFF_WPK    OFF_MEAN                 // packed Wih1 u32 3072*768 (9.4MB)
                                            // overlays mean+tmp (dead by then)

// agent-scope write-through stores (coherence point; proven r6)
__device__ __forceinline__ void coh_store_u16(unsigned short* p, unsigned short v) {
  __hip_atomic_store(p, v, __ATOMIC_RELAXED, __HIP_MEMORY_SCOPE_AGENT);
}

// split a float into RNE bf16 hi + bf16 residual
__device__ __forceinline__ void split_bf16(float v, unsigned short& hi,
                                           unsigned short& lo) {
  const unsigned u = __float_as_uint(v);
  const unsigned r = u + 0x7FFFu + ((u >> 16) & 1u);   // round-to-nearest-even
  hi = (unsigned short)(r >> 16);
  const float rem = v - __uint_as_float((r >> 16) << 16);
  lo = (unsigned short)(__float_as_uint(rem) >> 16);
}

// RNE bf16 only (recurrence h store)
__device__ __forceinline__ unsigned short rne_bf16(float v) {
  const unsigned u = __float_as_uint(v);
  return (unsigned short)((u + 0x7FFFu + ((u >> 16) & 1u)) >> 16);
}

// pack a float to (hi<<16)|lo
__device__ __forceinline__ unsigned pack_hilo(float v) {
  unsigned short h, l;
  split_bf16(v, h, l);
  return ((unsigned)h << 16) | l;
}

// unpack 8 packed u32 -> bf16x8 hi/lo fragments (2 shifts/elem)
__device__ __forceinline__ void unpack8(const uint4& a, const uint4& b,
                                        bf16x8& hi, bf16x8& lo) {
  const unsigned ww[8] = {a.x, a.y, a.z, a.w, b.x, b.y, b.z, b.w};
  #pragma unroll
  for (int i = 0; i < 8; ++i) {
    hi[i] = (short)(ww[i] >> 16);
    lo[i] = (short)(ww[i] & 0xffffu);
  }
}

// stage bf16 h [32][768] u16 global -> LDS plane: pure 16B copies, no VALU
__device__ __forceinline__ void stage_hi(const unsigned short* __restrict__ src,
                                         unsigned short* plane, int sb, int sch) {
  #pragma unroll
  for (int it = 0; it < 6; ++it) {
    const int k0 = (sch + it * 16) * 8;
    uint4 v = *(const uint4*)(src + (size_t)sb * NH + k0);
    *(uint4*)(&plane[sb * HP2 + k0]) = v;
  }
}

// ---------------------------------------------------------------------------
// Segment mean: encs [65536,768] -> mean [2048,768]
// ---------------------------------------------------------------------------
__global__ __launch_bounds__(192) void seg_mean_kernel(
    const float* __restrict__ encs, float* __restrict__ mean) {
  const int s = blockIdx.x;
  const int t = threadIdx.x;
  const float4* base = (const float4*)(encs + (size_t)s * 32 * NH);
  float4 a = {0.f, 0.f, 0.f, 0.f};
  #pragma unroll 4
  for (int r = 0; r < 32; ++r) {
    float4 v = base[(size_t)r * (NH / 4) + t];
    a.x += v.x; a.y += v.y; a.z += v.z; a.w += v.w;
  }
  const float inv = 1.f / 32.f;
  float4 o = {a.x * inv, a.y * inv, a.z * inv, a.w * inv};
  ((float4*)mean)[(size_t)s * (NH / 4) + t] = o;
}

// ---------------------------------------------------------------------------
// 32x32 LDS-tiled transpose: dst[j][i] = src[i][j]  (n x n, n % 32 == 0)
// ---------------------------------------------------------------------------
__global__ __launch_bounds__(256) void transpose_kernel(
    const float* __restrict__ src, float* __restrict__ dst, int n) {
  __shared__ float tile[32][33];
  const int nt = n / 32;
  const int bx = blockIdx.x % nt, by = blockIdx.x / nt;
  const int tx = threadIdx.x & 31, ty = threadIdx.x >> 5;   // 8 rows/pass
  #pragma unroll
  for (int i = 0; i < 32; i += 8)
    tile[ty + i][tx] = src[(size_t)(by * 32 + ty + i) * n + bx * 32 + tx];
  __syncthreads();
  #pragma unroll
  for (int i = 0; i < 32; i += 8)
    dst[(size_t)(bx * 32 + ty + i) * n + by * 32 + tx] = tile[tx][ty + i];
}

// ---------------------------------------------------------------------------
// b12[i] = sum_k W2[i,k]*b1[k] + b2[i]
// ---------------------------------------------------------------------------
__global__ __launch_bounds__(256) void b12_kernel(
    const float* __restrict__ W2, const float* __restrict__ b1,
    const float* __restrict__ b2, float* __restrict__ b12) {
  const int i = blockIdx.x * 256 + threadIdx.x;
  if (i >= NH) return;
  float acc = b2[i];
  for (int k = 0; k < NH; ++k) acc += W2[(size_t)i * NH + k] * b1[k];
  b12[i] = acc;
}

// ---------------------------------------------------------------------------
// Split-bf16 MFMA GEMM (64x64 tile, f32 in), round-10 proven.
// C[M,N] = A[M,K] @ W[N,K]^T + bias1[n] + bias2[n]
// ---------------------------------------------------------------------------
__global__ __launch_bounds__(256) void gemm_mfma_nt(
    const float* __restrict__ A, const float* __restrict__ W,
    const float* __restrict__ bias1, const float* __restrict__ bias2,
    float* __restrict__ C, int M, int N, int K) {
  __shared__ unsigned short Ahi[64 * 40];
  __shared__ unsigned short Alo[64 * 40];
  __shared__ unsigned short Whi[64 * 40];
  __shared__ unsigned short Wlo[64 * 40];
  const int tid = threadIdx.x;
  const int bm = blockIdx.y, bn = blockIdx.x;
  const int lane = tid & 63;
  const int wid  = tid >> 6;
  const int lm = lane & 15;
  const int lk = lane >> 4;
  const int srow = tid >> 2;
  const int skc  = (tid & 3) * 8;

  const float* Ap = A + (size_t)(bm * 64 + srow) * K;
  const float* Wp = W + (size_t)(bn * 64 + srow) * K;

  f32x4 acc[4];
  #pragma unroll
  for (int nf = 0; nf < 4; ++nf) acc[nf] = (f32x4){0.f, 0.f, 0.f, 0.f};

  for (int k0 = 0; k0 < K; k0 += 32) {
    float va[8], vw[8];
    if (k0 + skc + 8 <= K) {
      float4 a0 = *(const float4*)(Ap + k0 + skc);
      float4 a1 = *(const float4*)(Ap + k0 + skc + 4);
      float4 w0 = *(const float4*)(Wp + k0 + skc);
      float4 w1 = *(const float4*)(Wp + k0 + skc + 4);
      va[0]=a0.x; va[1]=a0.y; va[2]=a0.z; va[3]=a0.w;
      va[4]=a1.x; va[5]=a1.y; va[6]=a1.z; va[7]=a1.w;
      vw[0]=w0.x; vw[1]=w0.y; vw[2]=w0.z; vw[3]=w0.w;
      vw[4]=w1.x; vw[5]=w1.y; vw[6]=w1.z; vw[7]=w1.w;
    } else {
      #pragma unroll
      for (int i = 0; i < 8; ++i) { va[i] = 0.f; vw[i] = 0.f; }
    }
    u16x8 AH, AL, WH, WL;
    #pragma unroll
    for (int i = 0; i < 8; ++i) {
      unsigned short h, l;
      split_bf16(va[i], h, l); AH[i] = h; AL[i] = l;
      split_bf16(vw[i], h, l); WH[i] = h; WL[i] = l;
    }
    __syncthreads();
    *(u16x8*)(&Ahi[srow * 40 + skc]) = AH;
    *(u16x8*)(&Alo[srow * 40 + skc]) = AL;
    *(u16x8*)(&Whi[srow * 40 + skc]) = WH;
    *(u16x8*)(&Wlo[srow * 40 + skc]) = WL;
    __syncthreads();
    bf16x8 ah = *(bf16x8*)(&Ahi[(wid * 16 + lm) * 40 + lk * 8]);
    bf16x8 al = *(bf16x8*)(&Alo[(wid * 16 + lm) * 40 + lk * 8]);
    #pragma unroll
    for (int nf = 0; nf < 4; ++nf) {
      bf16x8 bh = *(bf16x8*)(&Whi[(nf * 16 + lm) * 40 + lk * 8]);
      bf16x8 bl = *(bf16x8*)(&Wlo[(nf * 16 + lm) * 40 + lk * 8]);
      acc[nf] = __builtin_amdgcn_mfma_f32_16x16x32_bf16(ah, bh, acc[nf], 0, 0, 0);
      acc[nf] = __builtin_amdgcn_mfma_f32_16x16x32_bf16(ah, bl, acc[nf], 0, 0, 0);
      acc[nf] = __builtin_amdgcn_mfma_f32_16x16x32_bf16(al, bh, acc[nf], 0, 0, 0);
    }
  }
  #pragma unroll
  for (int nf = 0; nf < 4; ++nf) {
    const int gn = bn * 64 + nf * 16 + lm;
    float bb = 0.f;
    if (bias1) bb += bias1[gn];
    if (bias2) bb += bias2[gn];
    #pragma unroll
    for (int r4 = 0; r4 < 4; ++r4) {
      const int gm = bm * 64 + wid * 16 + lk * 4 + r4;
      C[(size_t)gm * N + gn] = acc[nf][r4] + bb;
    }
  }
}

// ---------------------------------------------------------------------------
// Pack fp32 -> (hi<<16|lo) u32, 4 elements per thread
// ---------------------------------------------------------------------------
__global__ __launch_bounds__(256) void pack_w_kernel(
    const float* __restrict__ src, unsigned* __restrict__ dst, int n4) {
  const int i = blockIdx.x * 256 + threadIdx.x;
  if (i >= n4) return;
  float4 v = ((const float4*)src)[i];
  uint4 o;
  o.x = pack_hilo(v.x); o.y = pack_hilo(v.y);
  o.z = pack_hilo(v.z); o.w = pack_hilo(v.w);
  ((uint4*)dst)[i] = o;
}

// ---------------------------------------------------------------------------
// x[s*32+b][0:816] = concat(z[b,s], cond[b,s], encoded[b*64+s])
// ---------------------------------------------------------------------------
__global__ __launch_bounds__(256) void build_x_kernel(
    const float* __restrict__ z, const float* __restrict__ cond,
    const float* __restrict__ enc, float* __restrict__ x) {
  const int idx = blockIdx.x * 256 + threadIdx.x;
  const int r = idx / NIN, c = idx % NIN;
  const int s = r >> 5, b = r & 31;
  const int bs = b * NS + s;
  float v;
  if (c < 32)      v = z[bs * 32 + c];
  else if (c < 48) v = cond[bs * 16 + (c - 32)];
  else             v = enc[(size_t)bs * NH + (c - 48)];
  x[idx] = v;
}

// ---------------------------------------------------------------------------
// MERGED 2-layer persistent LSTM (round-17 proven) with ONE change: L1
// phase-A weight fragments come from PRE-PACKED Wih1 (hi<<16|lo u32) --
// unpack is 2 shifts/elem instead of ~6-op split_bf16 (bit-identical
// operands, numerics unchanged).  Everything else byte-identical to r17.
// ---------------------------------------------------------------------------
__global__ __launch_bounds__(LTHR)
__attribute__((amdgpu_waves_per_eu(2, 2)))
void lstm_merged(
    const float* __restrict__ xg0,    // [64*32][3072] layer-0 gates (biases folded)
    const float* __restrict__ Whh0,   // [3072][768]
    const unsigned* __restrict__ Wih1pk, // [3072][768] packed hi|lo
    const float* __restrict__ Whh1,   // [3072][768]
    const float* __restrict__ bih1,   // [3072]
    const float* __restrict__ bhh1,   // [3072]
    const unsigned short* __restrict__ hzero, // [32][768] bf16 zeros
    unsigned short* h0,               // [2048][768] bf16, row = t*32+b
    unsigned short* h1,               // [2048][768] bf16
    unsigned* flags) {                // 192 slots at stride 4 u32, zeroed
  extern __shared__ __align__(16) unsigned short smem_us[];
  unsigned short* pA  = smem_us;                 // [32][HP2] bf16(h0)
  unsigned short* pB  = smem_us + 32 * HP2;      // [32][HP2] bf16(h1)
  float*          gsp = (float*)(smem_us + 2 * 32 * HP2);  // [8][16][33]

  const int tid  = threadIdx.x;
  const int lane = tid & 63;
  const int wid  = tid >> 6;          // 0..7
  const bool wL1 = (wid >= 4);        // waves 4-7 compute layer-1 products
  const int kh   = wid & 3;           // K-quarter (k = kh*192 .. +192)
  const int lm   = lane & 15;
  const int lk   = lane >> 4;
  const int lblk = blockIdx.x;

  // resident Whh frags (L0 or L1 depending on wave -- same registers)
  const int grow = (lm >> 2) * NH + lblk * 4 + (lm & 3);  // gate-row (M=16)
  const float* WhhP = wL1 ? Whh1 : Whh0;
  bf16x8 whi[6], wlo[6];
  #pragma unroll
  for (int s6 = 0; s6 < 6; ++s6) {
    const float* wp = WhhP + (size_t)grow * NH + kh * 192 + s6 * 32 + lk * 8;
    float4 a = *(const float4*)wp;
    float4 b = *(const float4*)(wp + 4);
    float vv[8] = {a.x, a.y, a.z, a.w, b.x, b.y, b.z, b.w};
    #pragma unroll
    for (int i = 0; i < 8; ++i) {
      unsigned short h, l;
      split_bf16(vv[i], h, l);
      whi[s6][i] = (short)h;
      wlo[s6][i] = (short)l;
    }
  }

  // pointwise (tid<256): jp = tid>>5 in 0..7; jp<4 -> L0 cell, else L1
  const int jp = tid >> 5;
  const int bp = tid & 31;
  const bool pwL1 = (jp >= 4);
  const int jloc = jp & 3;
  float c_reg = 0.f;
  float bi = 0.f, bf_ = 0.f, bg = 0.f, bo = 0.f;
  if (tid < 256 && pwL1) {
    const int jj = lblk * 4 + jloc;
    bi  = bih1[0 * NH + jj] + bhh1[0 * NH + jj];
    bf_ = bih1[1 * NH + jj] + bhh1[1 * NH + jj];
    bg  = bih1[2 * NH + jj] + bhh1[2 * NH + jj];
    bo  = bih1[3 * NH + jj] + bhh1[3 * NH + jj];
  }
  const int sb  = tid >> 4;          // staging batch 0..31
  const int sch = tid & 15;          // staging chunk

  for (int e = 0; e <= NS; ++e) {
    const unsigned short* h0r = (e == 0) ? hzero : h0 + (size_t)(e - 1) * NB * NH;
    const unsigned short* h1r = (e <= 1) ? hzero : h1 + (size_t)(e - 2) * NB * NH;
    // L0 xg prefetch (hides under staging/MFMA)
    float xgv0 = 0.f, xgv1 = 0.f, xgv2 = 0.f, xgv3 = 0.f;
    if (tid < 256 && !pwL1 && e < NS) {
      const float* xr = xg0 + (size_t)(e * NB + bp) * G4 + (lblk * 4 + jloc);
      xgv0 = xr[0]; xgv1 = xr[NH]; xgv2 = xr[2 * NH]; xgv3 = xr[3 * NH];
    }
    // ---- stage BOTH planes at epoch top: LLC round-trips overlap ----
    stage_hi(h0r, pA, sb, sch);
    stage_hi(h1r, pB, sb, sch);
    __syncthreads();
    f32x4 acc0 = {0.f, 0.f, 0.f, 0.f};
    f32x4 acc1 = {0.f, 0.f, 0.f, 0.f};
    if (!wL1) {
      // L0: gates = Whh0 . h0(e-1)   (2 products: weight hi + weight lo)
      #pragma unroll
      for (int s6 = 0; s6 < 6; ++s6) {
        const int kb = kh * 192 + s6 * 32 + lk * 8;
        bf16x8 b0 = *(bf16x8*)(&pA[lm * HP2 + kb]);
        bf16x8 b1 = *(bf16x8*)(&pA[(16 + lm) * HP2 + kb]);
        acc0 = __builtin_amdgcn_mfma_f32_16x16x32_bf16(whi[s6], b0, acc0, 0, 0, 0);
        acc0 = __builtin_amdgcn_mfma_f32_16x16x32_bf16(wlo[s6], b0, acc0, 0, 0, 0);
        acc1 = __builtin_amdgcn_mfma_f32_16x16x32_bf16(whi[s6], b1, acc1, 0, 0, 0);
        acc1 = __builtin_amdgcn_mfma_f32_16x16x32_bf16(wlo[s6], b1, acc1, 0, 0, 0);
      }
    } else {
      // L1 phase A: acc = Wih1 . h0(e-1)  (packed u-frags, L2-hot)
      #pragma unroll
      for (int s6 = 0; s6 < 6; ++s6) {
        const unsigned* up = Wih1pk + (size_t)grow * NH + kh * 192 + s6 * 32 + lk * 8;
        uint4 ua = *(const uint4*)up;
        uint4 ub = *(const uint4*)(up + 4);
        bf16x8 uh, ul;
        unpack8(ua, ub, uh, ul);
        const int kb = kh * 192 + s6 * 32 + lk * 8;
        bf16x8 b0 = *(bf16x8*)(&pA[lm * HP2 + kb]);
        bf16x8 b1 = *(bf16x8*)(&pA[(16 + lm) * HP2 + kb]);
        acc0 = __builtin_amdgcn_mfma_f32_16x16x32_bf16(uh, b0, acc0, 0, 0, 0);
        acc0 = __builtin_amdgcn_mfma_f32_16x16x32_bf16(ul, b0, acc0, 0, 0, 0);
        acc1 = __builtin_amdgcn_mfma_f32_16x16x32_bf16(uh, b1, acc1, 0, 0, 0);
        acc1 = __builtin_amdgcn_mfma_f32_16x16x32_bf16(ul, b1, acc1, 0, 0, 0);
      }
      // L1 phase B: acc += Whh1 . h1(e-2)  (resident frags, plane B)
      #pragma unroll
      for (int s6 = 0; s6 < 6; ++s6) {
        const int kb = kh * 192 + s6 * 32 + lk * 8;
        bf16x8 b0 = *(bf16x8*)(&pB[lm * HP2 + kb]);
        bf16x8 b1 = *(bf16x8*)(&pB[(16 + lm) * HP2 + kb]);
        acc0 = __builtin_amdgcn_mfma_f32_16x16x32_bf16(whi[s6], b0, acc0, 0, 0, 0);
        acc0 = __builtin_amdgcn_mfma_f32_16x16x32_bf16(wlo[s6], b0, acc0, 0, 0, 0);
        acc1 = __builtin_amdgcn_mfma_f32_16x16x32_bf16(whi[s6], b1, acc1, 0, 0, 0);
        acc1 = __builtin_amdgcn_mfma_f32_16x16x32_bf16(wlo[s6], b1, acc1, 0, 0, 0);
      }
    }
    #pragma unroll
    for (int r4 = 0; r4 < 4; ++r4) {
      gsp[wid * 528 + (lk * 4 + r4) * 33 + lm]      = acc0[r4];
      gsp[wid * 528 + (lk * 4 + r4) * 33 + 16 + lm] = acc1[r4];
    }
    __syncthreads();
    // ---- pointwise for both layers ----
    if (tid < 256) {
      if (!pwL1) {
        if (e < NS) {
          float sum[4];
          #pragma unroll
          for (int g = 0; g < 4; ++g) {
            const int row = g * 4 + jloc;
            sum[g] = gsp[0 * 528 + row * 33 + bp] + gsp[1 * 528 + row * 33 + bp] +
                     gsp[2 * 528 + row * 33 + bp] + gsp[3 * 528 + row * 33 + bp];
          }
          const float si = 1.f / (1.f + expf(-(sum[0] + xgv0)));
          const float sf = 1.f / (1.f + expf(-(sum[1] + xgv1)));
          const float so = 1.f / (1.f + expf(-(sum[3] + xgv3)));
          c_reg = sf * c_reg + si * tanhf(sum[2] + xgv2);
          const float hnew = so * tanhf(c_reg);
          coh_store_u16(&h0[(size_t)(e * NB + bp) * NH + lblk * 4 + jloc],
                        rne_bf16(hnew));
        }
      } else {
        if (e >= 1) {
          const int t = e - 1;
          float sum[4];
          #pragma unroll
          for (int g = 0; g < 4; ++g) {
            const int row = g * 4 + jloc;
            sum[g] = gsp[4 * 528 + row * 33 + bp] + gsp[5 * 528 + row * 33 + bp] +
                     gsp[6 * 528 + row * 33 + bp] + gsp[7 * 528 + row * 33 + bp];
          }
          const float si = 1.f / (1.f + expf(-(sum[0] + bi)));
          const float sf = 1.f / (1.f + expf(-(sum[1] + bf_)));
          const float so = 1.f / (1.f + expf(-(sum[3] + bo)));
          c_reg = sf * c_reg + si * tanhf(sum[2] + bg);
          const float hnew = so * tanhf(c_reg);
          coh_store_u16(&h1[(size_t)(t * NB + bp) * NH + lblk * 4 + jloc],
                        rne_bf16(hnew));
        }
      }
    }
    // ---- flag-array grid barrier (epochs 0..63; epoch 64 ends kernel) ----
    if (e < NS) {
      __syncthreads();                 // all waves' h stores issued
      if (tid == 0) {
        asm volatile("s_waitcnt vmcnt(0)" ::: "memory");
        __hip_atomic_store(&flags[(unsigned)blockIdx.x * 4], (unsigned)(e + 1),
                           __ATOMIC_RELAXED, __HIP_MEMORY_SCOPE_AGENT);
      }
      if (tid < FBLK) {
        while (__hip_atomic_load(&flags[(unsigned)tid * 4], __ATOMIC_RELAXED,
                                 __HIP_MEMORY_SCOPE_AGENT) < (unsigned)(e + 1))
          __builtin_amdgcn_s_sleep(1);
      }
      __syncthreads();
    }
  }
}

// ---------------------------------------------------------------------------
// preds[b*24+s] = dot(bf16(h1[s*32+b]), Wout) + bout
// ---------------------------------------------------------------------------
__global__ __launch_bounds__(64) void head_kernel(
    const unsigned short* __restrict__ h1, const float* __restrict__ Wout,
    const float* __restrict__ bout, float* __restrict__ preds) {
  const int o = blockIdx.x;
  const int b = o / HOR_, s = o % HOR_;
  const int l = threadIdx.x;
  const unsigned short* h = h1 + (size_t)(s * NB + b) * NH;
  float acc = 0.f;
  #pragma unroll
  for (int k = l; k < NH; k += 64) {
    const float v = __uint_as_float(((unsigned)h[k]) << 16);
    acc += v * Wout[k];
  }
  #pragma unroll
  for (int m = 32; m; m >>= 1) acc += __shfl_xor(acc, m);
  if (l == 0) preds[o] = acc + bout[0];
}

// ---------------------------------------------------------------------------
extern "C" void kernel_launch(void* const* d_in, const int* in_sizes, int n_in,
                              void* d_out, int out_size, void* d_ws, size_t ws_size,
                              hipStream_t stream) {
  const float* z    = (const float*)d_in[0];
  const float* cond = (const float*)d_in[1];
  const float* encs = (const float*)d_in[2];
  const float* W1   = (const float*)d_in[4];
  const float* b1   = (const float*)d_in[5];
  const float* W2   = (const float*)d_in[6];
  const float* b2   = (const float*)d_in[7];
  const float* Wih0 = (const float*)d_in[8];
  const float* Whh0 = (const float*)d_in[9];
  const float* bih0 = (const float*)d_in[10];
  const float* bhh0 = (const float*)d_in[11];
  const float* Wih1 = (const float*)d_in[12];
  const float* Whh1 = (const float*)d_in[13];
  const float* bih1 = (const float*)d_in[14];
  const float* bhh1 = (const float*)d_in[15];
  const float* Wout = (const float*)d_in[16];
  const float* bout = (const float*)d_in[17];

  float* out     = (float*)d_out;
  float* preds   = out;
  float* enc_out = out + NB * HOR_;

  float* ws    = (float*)d_ws;
  float* xb    = ws + OFF_X;
  float* mean  = ws + OFF_MEAN;
  float* w1t   = ws + OFF_W1T;
  float* w12   = ws + OFF_W12;
  float* b12   = ws + OFF_B12;
  unsigned* wih1pk = (unsigned*)(ws + OFF_WPK);
  unsigned short* h0 = (unsigned short*)(ws + OFF_H0PK);
  unsigned short* h1 = (unsigned short*)(ws + OFF_H1PK);
  float* xg    = ws + OFF_XG;
  unsigned short* hzero = (unsigned short*)(ws + OFF_HZERO);
  unsigned* flags = (unsigned*)(ws + OFF_FLG);

  // allow >64KB dynamic LDS for the persistent kernel
  (void)hipFuncSetAttribute(reinterpret_cast<const void*>(lstm_merged),
                            hipFuncAttributeMaxDynamicSharedMemorySize,
                            160 * 1024);

  // 1. segment mean (filter and mean are linear and commute -> pool first)
  seg_mean_kernel<<<NSEG_, 192, 0, stream>>>(encs, mean);
  // 2. fold the two filter layers: W12 = W2@W1, b12 = W2@b1 + b2
  transpose_kernel<<<(NH / 32) * (NH / 32), 256, 0, stream>>>(W1, w1t, NH);
  gemm_mfma_nt<<<dim3(NH / 64, NH / 64), 256, 0, stream>>>(
      W2, w1t, nullptr, nullptr, w12, NH, NH, NH);
  b12_kernel<<<(NH + 255) / 256, 256, 0, stream>>>(W2, b1, b2, b12);
  //    encoded = mean @ W12^T + b12 -> straight into d_out (ONE GEMM)
  gemm_mfma_nt<<<dim3(NH / 64, NSEG_ / 64), 256, 0, stream>>>(
      mean, w12, b12, nullptr, enc_out, NSEG_, NH, NH);
  // 3. x = concat(z, cond, encoded); pack Wih1 (mean/tmp region now dead)
  build_x_kernel<<<(NSEG_ * NIN) / 256, 256, 0, stream>>>(z, cond, enc_out, xb);
  pack_w_kernel<<<(G4 * NH / 4 + 255) / 256, 256, 0, stream>>>(
      Wih1, wih1pk, G4 * NH / 4);
  // 4. layer-0 input gates (biases folded in), K=816 (guarded chunks)
  gemm_mfma_nt<<<dim3(G4 / 64, NSEG_ / 64), 256, 0, stream>>>(
      xb, Wih0, bih0, bhh0, xg, NSEG_, G4, NIN);
  // 5. merged, pipelined 2-layer recurrence (layer-1 xg GEMM folded in)
  hipMemsetAsync(hzero, 0, (size_t)(SZ_HZERO + 1024) * sizeof(float), stream);
  lstm_merged<<<FBLK, LTHR, SMEM_BYTES, stream>>>(
      xg, Whh0, wih1pk, Whh1, bih1, bhh1, hzero, h0, h1, flags);
  // 6. head
  head_kernel<<<NB * HOR_, 64, 0, stream>>>(h1, Wout, bout, preds);
}

// Round 20
// 571.042 us; speedup vs baseline: 1.0430x; 1.0430x over previous
//
#include <hip/hip_runtime.h>
#include <cstddef>

#define NB 32
#define NS 64
#define NH 768
#define NSEG_ (NB*NS)      // 2048
#define NIN 816
#define G4 3072
#define HOR_ 24
#define FBLK 192           // merged blocks: each owns 4 j of L0 + 4 j of L1
#define LTHR 512           // 8 waves/block

// MFMA fragment types (short-based bf16, compile-verified on gfx950)
typedef __attribute__((ext_vector_type(8))) short bf16x8;
typedef __attribute__((ext_vector_type(4))) float f32x4;
typedef __attribute__((ext_vector_type(8))) unsigned short u16x8;

// lstm dynamic-LDS: TWO bf16 h planes [32][776 u16] + partial-C [8][16][33]
#define HP2 776            // plane row stride in u16 (768 + 8 pad; 16B-aligned)
#define SMEM_BYTES (2*32*HP2*2 + 8*528*4)   // 99328 + 16896 = 116224

// workspace offsets (floats)
#define OFF_X      0
#define SZ_X       (NSEG_*NIN)
#define OFF_MEAN   (OFF_X + SZ_X)
#define SZ_MEAN    (NSEG_*NH)
#define OFF_TMP    (OFF_MEAN + SZ_MEAN)
#define OFF_H0PK   (OFF_TMP + SZ_MEAN)      // [2048][768] bf16 u16
#define OFF_H1PK   (OFF_H0PK + SZ_MEAN)
#define OFF_XG     (OFF_H1PK + SZ_MEAN)
#define SZ_XG      (NSEG_*G4)
#define OFF_HZERO  (OFF_XG + SZ_XG)
#define SZ_HZERO   (NB*NH)
#define OFF_FLG    (OFF_HZERO + SZ_HZERO)   // 192 flag slots, 16B apart
// packed Wih1 u32 (3072*768 = 9.4 MB) overlays mean+tmp (dead after filter)
#define OFF_WPK    OFF_MEAN

// agent-scope write-through stores (coherence point; proven r6)
__device__ __forceinline__ void coh_store_u16(unsigned short* p, unsigned short v) {
  __hip_atomic_store(p, v, __ATOMIC_RELAXED, __HIP_MEMORY_SCOPE_AGENT);
}

// split a float into RNE bf16 hi + bf16 residual
__device__ __forceinline__ void split_bf16(float v, unsigned short& hi,
                                           unsigned short& lo) {
  const unsigned u = __float_as_uint(v);
  const unsigned r = u + 0x7FFFu + ((u >> 16) & 1u);   // round-to-nearest-even
  hi = (unsigned short)(r >> 16);
  const float rem = v - __uint_as_float((r >> 16) << 16);
  lo = (unsigned short)(__float_as_uint(rem) >> 16);
}

// RNE bf16 only (recurrence h store)
__device__ __forceinline__ unsigned short rne_bf16(float v) {
  const unsigned u = __float_as_uint(v);
  return (unsigned short)((u + 0x7FFFu + ((u >> 16) & 1u)) >> 16);
}

// pack a float to (hi<<16)|lo
__device__ __forceinline__ unsigned pack_hilo(float v) {
  unsigned short h, l;
  split_bf16(v, h, l);
  return ((unsigned)h << 16) | l;
}

// unpack 8 packed u32 -> bf16x8 hi/lo fragments (2 shifts/elem)
__device__ __forceinline__ void unpack8(const uint4& a, const uint4& b,
                                        bf16x8& hi, bf16x8& lo) {
  const unsigned ww[8] = {a.x, a.y, a.z, a.w, b.x, b.y, b.z, b.w};
  #pragma unroll
  for (int i = 0; i < 8; ++i) {
    hi[i] = (short)(ww[i] >> 16);
    lo[i] = (short)(ww[i] & 0xffffu);
  }
}

// stage bf16 h [32][768] u16 global -> LDS plane: pure 16B copies, no VALU
__device__ __forceinline__ void stage_hi(const unsigned short* __restrict__ src,
                                         unsigned short* plane, int sb, int sch) {
  #pragma unroll
  for (int it = 0; it < 6; ++it) {
    const int k0 = (sch + it * 16) * 8;
    uint4 v = *(const uint4*)(src + (size_t)sb * NH + k0);
    *(uint4*)(&plane[sb * HP2 + k0]) = v;
  }
}

// ---------------------------------------------------------------------------
// Segment mean: encs [65536,768] -> mean [2048,768]
// ---------------------------------------------------------------------------
__global__ __launch_bounds__(192) void seg_mean_kernel(
    const float* __restrict__ encs, float* __restrict__ mean) {
  const int s = blockIdx.x;
  const int t = threadIdx.x;
  const float4* base = (const float4*)(encs + (size_t)s * 32 * NH);
  float4 a = {0.f, 0.f, 0.f, 0.f};
  #pragma unroll 4
  for (int r = 0; r < 32; ++r) {
    float4 v = base[(size_t)r * (NH / 4) + t];
    a.x += v.x; a.y += v.y; a.z += v.z; a.w += v.w;
  }
  const float inv = 1.f / 32.f;
  float4 o = {a.x * inv, a.y * inv, a.z * inv, a.w * inv};
  ((float4*)mean)[(size_t)s * (NH / 4) + t] = o;
}

// ---------------------------------------------------------------------------
// Split-bf16 MFMA GEMM (64x64 tile, f32 in), round-10 proven.
// C[M,N] = A[M,K] @ W[N,K]^T + bias1[n] + bias2[n]
// ---------------------------------------------------------------------------
__global__ __launch_bounds__(256) void gemm_mfma_nt(
    const float* __restrict__ A, const float* __restrict__ W,
    const float* __restrict__ bias1, const float* __restrict__ bias2,
    float* __restrict__ C, int M, int N, int K) {
  __shared__ unsigned short Ahi[64 * 40];
  __shared__ unsigned short Alo[64 * 40];
  __shared__ unsigned short Whi[64 * 40];
  __shared__ unsigned short Wlo[64 * 40];
  const int tid = threadIdx.x;
  const int bm = blockIdx.y, bn = blockIdx.x;
  const int lane = tid & 63;
  const int wid  = tid >> 6;
  const int lm = lane & 15;
  const int lk = lane >> 4;
  const int srow = tid >> 2;
  const int skc  = (tid & 3) * 8;

  const float* Ap = A + (size_t)(bm * 64 + srow) * K;
  const float* Wp = W + (size_t)(bn * 64 + srow) * K;

  f32x4 acc[4];
  #pragma unroll
  for (int nf = 0; nf < 4; ++nf) acc[nf] = (f32x4){0.f, 0.f, 0.f, 0.f};

  for (int k0 = 0; k0 < K; k0 += 32) {
    float va[8], vw[8];
    if (k0 + skc + 8 <= K) {
      float4 a0 = *(const float4*)(Ap + k0 + skc);
      float4 a1 = *(const float4*)(Ap + k0 + skc + 4);
      float4 w0 = *(const float4*)(Wp + k0 + skc);
      float4 w1 = *(const float4*)(Wp + k0 + skc + 4);
      va[0]=a0.x; va[1]=a0.y; va[2]=a0.z; va[3]=a0.w;
      va[4]=a1.x; va[5]=a1.y; va[6]=a1.z; va[7]=a1.w;
      vw[0]=w0.x; vw[1]=w0.y; vw[2]=w0.z; vw[3]=w0.w;
      vw[4]=w1.x; vw[5]=w1.y; vw[6]=w1.z; vw[7]=w1.w;
    } else {
      #pragma unroll
      for (int i = 0; i < 8; ++i) { va[i] = 0.f; vw[i] = 0.f; }
    }
    u16x8 AH, AL, WH, WL;
    #pragma unroll
    for (int i = 0; i < 8; ++i) {
      unsigned short h, l;
      split_bf16(va[i], h, l); AH[i] = h; AL[i] = l;
      split_bf16(vw[i], h, l); WH[i] = h; WL[i] = l;
    }
    __syncthreads();
    *(u16x8*)(&Ahi[srow * 40 + skc]) = AH;
    *(u16x8*)(&Alo[srow * 40 + skc]) = AL;
    *(u16x8*)(&Whi[srow * 40 + skc]) = WH;
    *(u16x8*)(&Wlo[srow * 40 + skc]) = WL;
    __syncthreads();
    bf16x8 ah = *(bf16x8*)(&Ahi[(wid * 16 + lm) * 40 + lk * 8]);
    bf16x8 al = *(bf16x8*)(&Alo[(wid * 16 + lm) * 40 + lk * 8]);
    #pragma unroll
    for (int nf = 0; nf < 4; ++nf) {
      bf16x8 bh = *(bf16x8*)(&Whi[(nf * 16 + lm) * 40 + lk * 8]);
      bf16x8 bl = *(bf16x8*)(&Wlo[(nf * 16 + lm) * 40 + lk * 8]);
      acc[nf] = __builtin_amdgcn_mfma_f32_16x16x32_bf16(ah, bh, acc[nf], 0, 0, 0);
      acc[nf] = __builtin_amdgcn_mfma_f32_16x16x32_bf16(ah, bl, acc[nf], 0, 0, 0);
      acc[nf] = __builtin_amdgcn_mfma_f32_16x16x32_bf16(al, bh, acc[nf], 0, 0, 0);
    }
  }
  #pragma unroll
  for (int nf = 0; nf < 4; ++nf) {
    const int gn = bn * 64 + nf * 16 + lm;
    float bb = 0.f;
    if (bias1) bb += bias1[gn];
    if (bias2) bb += bias2[gn];
    #pragma unroll
    for (int r4 = 0; r4 < 4; ++r4) {
      const int gm = bm * 64 + wid * 16 + lk * 4 + r4;
      C[(size_t)gm * N + gn] = acc[nf][r4] + bb;
    }
  }
}

// ---------------------------------------------------------------------------
// Pack fp32 -> (hi<<16|lo) u32, 4 elements per thread
// ---------------------------------------------------------------------------
__global__ __launch_bounds__(256) void pack_w_kernel(
    const float* __restrict__ src, unsigned* __restrict__ dst, int n4) {
  const int i = blockIdx.x * 256 + threadIdx.x;
  if (i >= n4) return;
  float4 v = ((const float4*)src)[i];
  uint4 o;
  o.x = pack_hilo(v.x); o.y = pack_hilo(v.y);
  o.z = pack_hilo(v.z); o.w = pack_hilo(v.w);
  ((uint4*)dst)[i] = o;
}

// ---------------------------------------------------------------------------
// x[s*32+b][0:816] = concat(z[b,s], cond[b,s], encoded[b*64+s])
// ---------------------------------------------------------------------------
__global__ __launch_bounds__(256) void build_x_kernel(
    const float* __restrict__ z, const float* __restrict__ cond,
    const float* __restrict__ enc, float* __restrict__ x) {
  const int idx = blockIdx.x * 256 + threadIdx.x;
  const int r = idx / NIN, c = idx % NIN;
  const int s = r >> 5, b = r & 31;
  const int bs = b * NS + s;
  float v;
  if (c < 32)      v = z[bs * 32 + c];
  else if (c < 48) v = cond[bs * 16 + (c - 32)];
  else             v = enc[(size_t)bs * NH + (c - 48)];
  x[idx] = v;
}

// ---------------------------------------------------------------------------
// MERGED 2-layer persistent LSTM (r19 lstm core, proven 425us: packed Wih1
// phase-A, bf16 h exchange, two LDS planes, flag barrier).
// ---------------------------------------------------------------------------
__global__ __launch_bounds__(LTHR)
__attribute__((amdgpu_waves_per_eu(2, 2)))
void lstm_merged(
    const float* __restrict__ xg0,    // [64*32][3072] layer-0 gates (biases folded)
    const float* __restrict__ Whh0,   // [3072][768]
    const unsigned* __restrict__ Wih1pk, // [3072][768] packed hi|lo
    const float* __restrict__ Whh1,   // [3072][768]
    const float* __restrict__ bih1,   // [3072]
    const float* __restrict__ bhh1,   // [3072]
    const unsigned short* __restrict__ hzero, // [32][768] bf16 zeros
    unsigned short* h0,               // [2048][768] bf16, row = t*32+b
    unsigned short* h1,               // [2048][768] bf16
    unsigned* flags) {                // 192 slots at stride 4 u32, zeroed
  extern __shared__ __align__(16) unsigned short smem_us[];
  unsigned short* pA  = smem_us;                 // [32][HP2] bf16(h0)
  unsigned short* pB  = smem_us + 32 * HP2;      // [32][HP2] bf16(h1)
  float*          gsp = (float*)(smem_us + 2 * 32 * HP2);  // [8][16][33]

  const int tid  = threadIdx.x;
  const int lane = tid & 63;
  const int wid  = tid >> 6;          // 0..7
  const bool wL1 = (wid >= 4);        // waves 4-7 compute layer-1 products
  const int kh   = wid & 3;           // K-quarter (k = kh*192 .. +192)
  const int lm   = lane & 15;
  const int lk   = lane >> 4;
  const int lblk = blockIdx.x;

  // resident Whh frags (L0 or L1 depending on wave -- same registers)
  const int grow = (lm >> 2) * NH + lblk * 4 + (lm & 3);  // gate-row (M=16)
  const float* WhhP = wL1 ? Whh1 : Whh0;
  bf16x8 whi[6], wlo[6];
  #pragma unroll
  for (int s6 = 0; s6 < 6; ++s6) {
    const float* wp = WhhP + (size_t)grow * NH + kh * 192 + s6 * 32 + lk * 8;
    float4 a = *(const float4*)wp;
    float4 b = *(const float4*)(wp + 4);
    float vv[8] = {a.x, a.y, a.z, a.w, b.x, b.y, b.z, b.w};
    #pragma unroll
    for (int i = 0; i < 8; ++i) {
      unsigned short h, l;
      split_bf16(vv[i], h, l);
      whi[s6][i] = (short)h;
      wlo[s6][i] = (short)l;
    }
  }

  // pointwise (tid<256): jp = tid>>5 in 0..7; jp<4 -> L0 cell, else L1
  const int jp = tid >> 5;
  const int bp = tid & 31;
  const bool pwL1 = (jp >= 4);
  const int jloc = jp & 3;
  float c_reg = 0.f;
  float bi = 0.f, bf_ = 0.f, bg = 0.f, bo = 0.f;
  if (tid < 256 && pwL1) {
    const int jj = lblk * 4 + jloc;
    bi  = bih1[0 * NH + jj] + bhh1[0 * NH + jj];
    bf_ = bih1[1 * NH + jj] + bhh1[1 * NH + jj];
    bg  = bih1[2 * NH + jj] + bhh1[2 * NH + jj];
    bo  = bih1[3 * NH + jj] + bhh1[3 * NH + jj];
  }
  const int sb  = tid >> 4;          // staging batch 0..31
  const int sch = tid & 15;          // staging chunk

  for (int e = 0; e <= NS; ++e) {
    const unsigned short* h0r = (e == 0) ? hzero : h0 + (size_t)(e - 1) * NB * NH;
    const unsigned short* h1r = (e <= 1) ? hzero : h1 + (size_t)(e - 2) * NB * NH;
    // L0 xg prefetch (hides under staging/MFMA)
    float xgv0 = 0.f, xgv1 = 0.f, xgv2 = 0.f, xgv3 = 0.f;
    if (tid < 256 && !pwL1 && e < NS) {
      const float* xr = xg0 + (size_t)(e * NB + bp) * G4 + (lblk * 4 + jloc);
      xgv0 = xr[0]; xgv1 = xr[NH]; xgv2 = xr[2 * NH]; xgv3 = xr[3 * NH];
    }
    // ---- stage BOTH planes at epoch top: LLC round-trips overlap ----
    stage_hi(h0r, pA, sb, sch);
    stage_hi(h1r, pB, sb, sch);
    __syncthreads();
    f32x4 acc0 = {0.f, 0.f, 0.f, 0.f};
    f32x4 acc1 = {0.f, 0.f, 0.f, 0.f};
    if (!wL1) {
      // L0: gates = Whh0 . h0(e-1)   (2 products: weight hi + weight lo)
      #pragma unroll
      for (int s6 = 0; s6 < 6; ++s6) {
        const int kb = kh * 192 + s6 * 32 + lk * 8;
        bf16x8 b0 = *(bf16x8*)(&pA[lm * HP2 + kb]);
        bf16x8 b1 = *(bf16x8*)(&pA[(16 + lm) * HP2 + kb]);
        acc0 = __builtin_amdgcn_mfma_f32_16x16x32_bf16(whi[s6], b0, acc0, 0, 0, 0);
        acc0 = __builtin_amdgcn_mfma_f32_16x16x32_bf16(wlo[s6], b0, acc0, 0, 0, 0);
        acc1 = __builtin_amdgcn_mfma_f32_16x16x32_bf16(whi[s6], b1, acc1, 0, 0, 0);
        acc1 = __builtin_amdgcn_mfma_f32_16x16x32_bf16(wlo[s6], b1, acc1, 0, 0, 0);
      }
    } else {
      // L1 phase A: acc = Wih1 . h0(e-1)  (packed u-frags, L2-hot)
      #pragma unroll
      for (int s6 = 0; s6 < 6; ++s6) {
        const unsigned* up = Wih1pk + (size_t)grow * NH + kh * 192 + s6 * 32 + lk * 8;
        uint4 ua = *(const uint4*)up;
        uint4 ub = *(const uint4*)(up + 4);
        bf16x8 uh, ul;
        unpack8(ua, ub, uh, ul);
        const int kb = kh * 192 + s6 * 32 + lk * 8;
        bf16x8 b0 = *(bf16x8*)(&pA[lm * HP2 + kb]);
        bf16x8 b1 = *(bf16x8*)(&pA[(16 + lm) * HP2 + kb]);
        acc0 = __builtin_amdgcn_mfma_f32_16x16x32_bf16(uh, b0, acc0, 0, 0, 0);
        acc0 = __builtin_amdgcn_mfma_f32_16x16x32_bf16(ul, b0, acc0, 0, 0, 0);
        acc1 = __builtin_amdgcn_mfma_f32_16x16x32_bf16(uh, b1, acc1, 0, 0, 0);
        acc1 = __builtin_amdgcn_mfma_f32_16x16x32_bf16(ul, b1, acc1, 0, 0, 0);
      }
      // L1 phase B: acc += Whh1 . h1(e-2)  (resident frags, plane B)
      #pragma unroll
      for (int s6 = 0; s6 < 6; ++s6) {
        const int kb = kh * 192 + s6 * 32 + lk * 8;
        bf16x8 b0 = *(bf16x8*)(&pB[lm * HP2 + kb]);
        bf16x8 b1 = *(bf16x8*)(&pB[(16 + lm) * HP2 + kb]);
        acc0 = __builtin_amdgcn_mfma_f32_16x16x32_bf16(whi[s6], b0, acc0, 0, 0, 0);
        acc0 = __builtin_amdgcn_mfma_f32_16x16x32_bf16(wlo[s6], b0, acc0, 0, 0, 0);
        acc1 = __builtin_amdgcn_mfma_f32_16x16x32_bf16(whi[s6], b1, acc1, 0, 0, 0);
        acc1 = __builtin_amdgcn_mfma_f32_16x16x32_bf16(wlo[s6], b1, acc1, 0, 0, 0);
      }
    }
    #pragma unroll
    for (int r4 = 0; r4 < 4; ++r4) {
      gsp[wid * 528 + (lk * 4 + r4) * 33 + lm]      = acc0[r4];
      gsp[wid * 528 + (lk * 4 + r4) * 33 + 16 + lm] = acc1[r4];
    }
    __syncthreads();
    // ---- pointwise for both layers ----
    if (tid < 256) {
      if (!pwL1) {
        if (e < NS) {
          float sum[4];
          #pragma unroll
          for (int g = 0; g < 4; ++g) {
            const int row = g * 4 + jloc;
            sum[g] = gsp[0 * 528 + row * 33 + bp] + gsp[1 * 528 + row * 33 + bp] +
                     gsp[2 * 528 + row * 33 + bp] + gsp[3 * 528 + row * 33 + bp];
          }
          const float si = 1.f / (1.f + expf(-(sum[0] + xgv0)));
          const float sf = 1.f / (1.f + expf(-(sum[1] + xgv1)));
          const float so = 1.f / (1.f + expf(-(sum[3] + xgv3)));
          c_reg = sf * c_reg + si * tanhf(sum[2] + xgv2);
          const float hnew = so * tanhf(c_reg);
          coh_store_u16(&h0[(size_t)(e * NB + bp) * NH + lblk * 4 + jloc],
                        rne_bf16(hnew));
        }
      } else {
        if (e >= 1) {
          const int t = e - 1;
          float sum[4];
          #pragma unroll
          for (int g = 0; g < 4; ++g) {
            const int row = g * 4 + jloc;
            sum[g] = gsp[4 * 528 + row * 33 + bp] + gsp[5 * 528 + row * 33 + bp] +
                     gsp[6 * 528 + row * 33 + bp] + gsp[7 * 528 + row * 33 + bp];
          }
          const float si = 1.f / (1.f + expf(-(sum[0] + bi)));
          const float sf = 1.f / (1.f + expf(-(sum[1] + bf_)));
          const float so = 1.f / (1.f + expf(-(sum[3] + bo)));
          c_reg = sf * c_reg + si * tanhf(sum[2] + bg);
          const float hnew = so * tanhf(c_reg);
          coh_store_u16(&h1[(size_t)(t * NB + bp) * NH + lblk * 4 + jloc],
                        rne_bf16(hnew));
        }
      }
    }
    // ---- flag-array grid barrier (epochs 0..63; epoch 64 ends kernel) ----
    if (e < NS) {
      __syncthreads();                 // all waves' h stores issued
      if (tid == 0) {
        asm volatile("s_waitcnt vmcnt(0)" ::: "memory");
        __hip_atomic_store(&flags[(unsigned)blockIdx.x * 4], (unsigned)(e + 1),
                           __ATOMIC_RELAXED, __HIP_MEMORY_SCOPE_AGENT);
      }
      if (tid < FBLK) {
        while (__hip_atomic_load(&flags[(unsigned)tid * 4], __ATOMIC_RELAXED,
                                 __HIP_MEMORY_SCOPE_AGENT) < (unsigned)(e + 1))
          __builtin_amdgcn_s_sleep(1);
      }
      __syncthreads();
    }
  }
}

// ---------------------------------------------------------------------------
// preds[b*24+s] = dot(bf16(h1[s*32+b]), Wout) + bout
// ---------------------------------------------------------------------------
__global__ __launch_bounds__(64) void head_kernel(
    const unsigned short* __restrict__ h1, const float* __restrict__ Wout,
    const float* __restrict__ bout, float* __restrict__ preds) {
  const int o = blockIdx.x;
  const int b = o / HOR_, s = o % HOR_;
  const int l = threadIdx.x;
  const unsigned short* h = h1 + (size_t)(s * NB + b) * NH;
  float acc = 0.f;
  #pragma unroll
  for (int k = l; k < NH; k += 64) {
    const float v = __uint_as_float(((unsigned)h[k]) << 16);
    acc += v * Wout[k];
  }
  #pragma unroll
  for (int m = 32; m; m >>= 1) acc += __shfl_xor(acc, m);
  if (l == 0) preds[o] = acc + bout[0];
}

// ---------------------------------------------------------------------------
extern "C" void kernel_launch(void* const* d_in, const int* in_sizes, int n_in,
                              void* d_out, int out_size, void* d_ws, size_t ws_size,
                              hipStream_t stream) {
  const float* z    = (const float*)d_in[0];
  const float* cond = (const float*)d_in[1];
  const float* encs = (const float*)d_in[2];
  const float* W1   = (const float*)d_in[4];
  const float* b1   = (const float*)d_in[5];
  const float* W2   = (const float*)d_in[6];
  const float* b2   = (const float*)d_in[7];
  const float* Wih0 = (const float*)d_in[8];
  const float* Whh0 = (const float*)d_in[9];
  const float* bih0 = (const float*)d_in[10];
  const float* bhh0 = (const float*)d_in[11];
  const float* Wih1 = (const float*)d_in[12];
  const float* Whh1 = (const float*)d_in[13];
  const float* bih1 = (const float*)d_in[14];
  const float* bhh1 = (const float*)d_in[15];
  const float* Wout = (const float*)d_in[16];
  const float* bout = (const float*)d_in[17];

  float* out     = (float*)d_out;
  float* preds   = out;
  float* enc_out = out + NB * HOR_;

  float* ws    = (float*)d_ws;
  float* xb    = ws + OFF_X;
  float* mean  = ws + OFF_MEAN;
  float* tmp   = ws + OFF_TMP;
  unsigned* wih1pk = (unsigned*)(ws + OFF_WPK);
  unsigned short* h0 = (unsigned short*)(ws + OFF_H0PK);
  unsigned short* h1 = (unsigned short*)(ws + OFF_H1PK);
  float* xg    = ws + OFF_XG;
  unsigned short* hzero = (unsigned short*)(ws + OFF_HZERO);
  unsigned* flags = (unsigned*)(ws + OFF_FLG);

  // allow >64KB dynamic LDS for the persistent kernel
  (void)hipFuncSetAttribute(reinterpret_cast<const void*>(lstm_merged),
                            hipFuncAttributeMaxDynamicSharedMemorySize,
                            160 * 1024);

  // 1. segment mean (filter and mean are linear and commute -> pool first)
  seg_mean_kernel<<<NSEG_, 192, 0, stream>>>(encs, mean);
  // 2. encoded = (mean @ W1^T + b1) @ W2^T + b2 -> straight into d_out (MFMA)
  gemm_mfma_nt<<<dim3(NH / 64, NSEG_ / 64), 256, 0, stream>>>(
      mean, W1, b1, nullptr, tmp, NSEG_, NH, NH);
  gemm_mfma_nt<<<dim3(NH / 64, NSEG_ / 64), 256, 0, stream>>>(
      tmp, W2, b2, nullptr, enc_out, NSEG_, NH, NH);
  // 3. x = concat(z, cond, encoded); pack Wih1 (mean/tmp region now dead)
  build_x_kernel<<<(NSEG_ * NIN) / 256, 256, 0, stream>>>(z, cond, enc_out, xb);
  pack_w_kernel<<<(G4 * NH / 4 + 255) / 256, 256, 0, stream>>>(
      Wih1, wih1pk, G4 * NH / 4);
  // 4. layer-0 input gates (biases folded in), K=816 (guarded chunks)
  gemm_mfma_nt<<<dim3(G4 / 64, NSEG_ / 64), 256, 0, stream>>>(
      xb, Wih0, bih0, bhh0, xg, NSEG_, G4, NIN);
  // 5. merged, pipelined 2-layer recurrence (layer-1 xg GEMM folded in)
  hipMemsetAsync(hzero, 0, (size_t)(SZ_HZERO + 1024) * sizeof(float), stream);
  lstm_merged<<<FBLK, LTHR, SMEM_BYTES, stream>>>(
      xg, Whh0, wih1pk, Whh1, bih1, bhh1, hzero, h0, h1, flags);
  // 6. head
  head_kernel<<<NB * HOR_, 64, 0, stream>>>(h1, Wout, bout, preds);
}

// Round 21
// 568.085 us; speedup vs baseline: 1.0485x; 1.0052x over previous
//
#include <hip/hip_runtime.h>
#include <cstddef>

#define NB 32
#define NS 64
#define NH 768
#define NSEG_ (NB*NS)      // 2048
#define NIN 816
#define G4 3072
#define HOR_ 24
#define FBLK 192           // merged blocks: each owns 4 j of L0 + 4 j of L1
#define LTHR 512           // 8 waves/block

// MFMA fragment types (short-based bf16, compile-verified on gfx950)
typedef __attribute__((ext_vector_type(8))) short bf16x8;
typedef __attribute__((ext_vector_type(4))) float f32x4;
typedef __attribute__((ext_vector_type(8))) unsigned short u16x8;

// lstm dynamic-LDS: TWO bf16 h planes [32][776 u16] + partial-C [8][16][33]
// + xg prefetch buffer [32][20] f32
#define HP2 776            // plane row stride in u16 (768 + 8 pad; 16B-aligned)
#define XBUF_F (32*20)     // 640 floats = 2560 B
#define SMEM_BYTES (2*32*HP2*2 + 8*528*4 + XBUF_F*4)   // 118784

// workspace offsets (floats)
#define OFF_X      0
#define SZ_X       (NSEG_*NIN)
#define OFF_MEAN   (OFF_X + SZ_X)
#define SZ_MEAN    (NSEG_*NH)
#define OFF_TMP    (OFF_MEAN + SZ_MEAN)
#define OFF_H0PK   (OFF_TMP + SZ_MEAN)      // [2048][768] bf16 u16
#define OFF_H1PK   (OFF_H0PK + SZ_MEAN)
#define OFF_XG     (OFF_H1PK + SZ_MEAN)
#define SZ_XG      (NSEG_*G4)
#define OFF_HZERO  (OFF_XG + SZ_XG)
#define SZ_HZERO   (NB*NH)
#define OFF_FLG    (OFF_HZERO + SZ_HZERO)   // 192 flag slots, 16B apart
// packed Wih1 u32 (3072*768 = 9.4 MB) overlays mean+tmp (dead after filter)
#define OFF_WPK    OFF_MEAN

// agent-scope write-through stores (coherence point; proven r6)
__device__ __forceinline__ void coh_store_u16(unsigned short* p, unsigned short v) {
  __hip_atomic_store(p, v, __ATOMIC_RELAXED, __HIP_MEMORY_SCOPE_AGENT);
}

// split a float into RNE bf16 hi + bf16 residual
__device__ __forceinline__ void split_bf16(float v, unsigned short& hi,
                                           unsigned short& lo) {
  const unsigned u = __float_as_uint(v);
  const unsigned r = u + 0x7FFFu + ((u >> 16) & 1u);   // round-to-nearest-even
  hi = (unsigned short)(r >> 16);
  const float rem = v - __uint_as_float((r >> 16) << 16);
  lo = (unsigned short)(__float_as_uint(rem) >> 16);
}

// RNE bf16 only (recurrence h store)
__device__ __forceinline__ unsigned short rne_bf16(float v) {
  const unsigned u = __float_as_uint(v);
  return (unsigned short)((u + 0x7FFFu + ((u >> 16) & 1u)) >> 16);
}

// pack a float to (hi<<16)|lo
__device__ __forceinline__ unsigned pack_hilo(float v) {
  unsigned short h, l;
  split_bf16(v, h, l);
  return ((unsigned)h << 16) | l;
}

// unpack 8 packed u32 -> bf16x8 hi/lo fragments (2 shifts/elem)
__device__ __forceinline__ void unpack8(const uint4& a, const uint4& b,
                                        bf16x8& hi, bf16x8& lo) {
  const unsigned ww[8] = {a.x, a.y, a.z, a.w, b.x, b.y, b.z, b.w};
  #pragma unroll
  for (int i = 0; i < 8; ++i) {
    hi[i] = (short)(ww[i] >> 16);
    lo[i] = (short)(ww[i] & 0xffffu);
  }
}

// stage bf16 h [32][768] u16 global -> LDS plane: pure 16B copies, no VALU
__device__ __forceinline__ void stage_hi(const unsigned short* __restrict__ src,
                                         unsigned short* plane, int sb, int sch) {
  #pragma unroll
  for (int it = 0; it < 6; ++it) {
    const int k0 = (sch + it * 16) * 8;
    uint4 v = *(const uint4*)(src + (size_t)sb * NH + k0);
    *(uint4*)(&plane[sb * HP2 + k0]) = v;
  }
}

// ---------------------------------------------------------------------------
// Segment mean: encs [65536,768] -> mean [2048,768]
// ---------------------------------------------------------------------------
__global__ __launch_bounds__(192) void seg_mean_kernel(
    const float* __restrict__ encs, float* __restrict__ mean) {
  const int s = blockIdx.x;
  const int t = threadIdx.x;
  const float4* base = (const float4*)(encs + (size_t)s * 32 * NH);
  float4 a = {0.f, 0.f, 0.f, 0.f};
  #pragma unroll 4
  for (int r = 0; r < 32; ++r) {
    float4 v = base[(size_t)r * (NH / 4) + t];
    a.x += v.x; a.y += v.y; a.z += v.z; a.w += v.w;
  }
  const float inv = 1.f / 32.f;
  float4 o = {a.x * inv, a.y * inv, a.z * inv, a.w * inv};
  ((float4*)mean)[(size_t)s * (NH / 4) + t] = o;
}

// ---------------------------------------------------------------------------
// Split-bf16 MFMA GEMM (64x64 tile, f32 in), round-10 proven.
// C[M,N] = A[M,K] @ W[N,K]^T + bias1[n] + bias2[n]
// ---------------------------------------------------------------------------
__global__ __launch_bounds__(256) void gemm_mfma_nt(
    const float* __restrict__ A, const float* __restrict__ W,
    const float* __restrict__ bias1, const float* __restrict__ bias2,
    float* __restrict__ C, int M, int N, int K) {
  __shared__ unsigned short Ahi[64 * 40];
  __shared__ unsigned short Alo[64 * 40];
  __shared__ unsigned short Whi[64 * 40];
  __shared__ unsigned short Wlo[64 * 40];
  const int tid = threadIdx.x;
  const int bm = blockIdx.y, bn = blockIdx.x;
  const int lane = tid & 63;
  const int wid  = tid >> 6;
  const int lm = lane & 15;
  const int lk = lane >> 4;
  const int srow = tid >> 2;
  const int skc  = (tid & 3) * 8;

  const float* Ap = A + (size_t)(bm * 64 + srow) * K;
  const float* Wp = W + (size_t)(bn * 64 + srow) * K;

  f32x4 acc[4];
  #pragma unroll
  for (int nf = 0; nf < 4; ++nf) acc[nf] = (f32x4){0.f, 0.f, 0.f, 0.f};

  for (int k0 = 0; k0 < K; k0 += 32) {
    float va[8], vw[8];
    if (k0 + skc + 8 <= K) {
      float4 a0 = *(const float4*)(Ap + k0 + skc);
      float4 a1 = *(const float4*)(Ap + k0 + skc + 4);
      float4 w0 = *(const float4*)(Wp + k0 + skc);
      float4 w1 = *(const float4*)(Wp + k0 + skc + 4);
      va[0]=a0.x; va[1]=a0.y; va[2]=a0.z; va[3]=a0.w;
      va[4]=a1.x; va[5]=a1.y; va[6]=a1.z; va[7]=a1.w;
      vw[0]=w0.x; vw[1]=w0.y; vw[2]=w0.z; vw[3]=w0.w;
      vw[4]=w1.x; vw[5]=w1.y; vw[6]=w1.z; vw[7]=w1.w;
    } else {
      #pragma unroll
      for (int i = 0; i < 8; ++i) { va[i] = 0.f; vw[i] = 0.f; }
    }
    u16x8 AH, AL, WH, WL;
    #pragma unroll
    for (int i = 0; i < 8; ++i) {
      unsigned short h, l;
      split_bf16(va[i], h, l); AH[i] = h; AL[i] = l;
      split_bf16(vw[i], h, l); WH[i] = h; WL[i] = l;
    }
    __syncthreads();
    *(u16x8*)(&Ahi[srow * 40 + skc]) = AH;
    *(u16x8*)(&Alo[srow * 40 + skc]) = AL;
    *(u16x8*)(&Whi[srow * 40 + skc]) = WH;
    *(u16x8*)(&Wlo[srow * 40 + skc]) = WL;
    __syncthreads();
    bf16x8 ah = *(bf16x8*)(&Ahi[(wid * 16 + lm) * 40 + lk * 8]);
    bf16x8 al = *(bf16x8*)(&Alo[(wid * 16 + lm) * 40 + lk * 8]);
    #pragma unroll
    for (int nf = 0; nf < 4; ++nf) {
      bf16x8 bh = *(bf16x8*)(&Whi[(nf * 16 + lm) * 40 + lk * 8]);
      bf16x8 bl = *(bf16x8*)(&Wlo[(nf * 16 + lm) * 40 + lk * 8]);
      acc[nf] = __builtin_amdgcn_mfma_f32_16x16x32_bf16(ah, bh, acc[nf], 0, 0, 0);
      acc[nf] = __builtin_amdgcn_mfma_f32_16x16x32_bf16(ah, bl, acc[nf], 0, 0, 0);
      acc[nf] = __builtin_amdgcn_mfma_f32_16x16x32_bf16(al, bh, acc[nf], 0, 0, 0);
    }
  }
  #pragma unroll
  for (int nf = 0; nf < 4; ++nf) {
    const int gn = bn * 64 + nf * 16 + lm;
    float bb = 0.f;
    if (bias1) bb += bias1[gn];
    if (bias2) bb += bias2[gn];
    #pragma unroll
    for (int r4 = 0; r4 < 4; ++r4) {
      const int gm = bm * 64 + wid * 16 + lk * 4 + r4;
      C[(size_t)gm * N + gn] = acc[nf][r4] + bb;
    }
  }
}

// ---------------------------------------------------------------------------
// Pack fp32 -> (hi<<16|lo) u32, 4 elements per thread
// ---------------------------------------------------------------------------
__global__ __launch_bounds__(256) void pack_w_kernel(
    const float* __restrict__ src, unsigned* __restrict__ dst, int n4) {
  const int i = blockIdx.x * 256 + threadIdx.x;
  if (i >= n4) return;
  float4 v = ((const float4*)src)[i];
  uint4 o;
  o.x = pack_hilo(v.x); o.y = pack_hilo(v.y);
  o.z = pack_hilo(v.z); o.w = pack_hilo(v.w);
  ((uint4*)dst)[i] = o;
}

// ---------------------------------------------------------------------------
// x[s*32+b][0:816] = concat(z[b,s], cond[b,s], encoded[b*64+s])
// ---------------------------------------------------------------------------
__global__ __launch_bounds__(256) void build_x_kernel(
    const float* __restrict__ z, const float* __restrict__ cond,
    const float* __restrict__ enc, float* __restrict__ x) {
  const int idx = blockIdx.x * 256 + threadIdx.x;
  const int r = idx / NIN, c = idx % NIN;
  const int s = r >> 5, b = r & 31;
  const int bs = b * NS + s;
  float v;
  if (c < 32)      v = z[bs * 32 + c];
  else if (c < 48) v = cond[bs * 16 + (c - 32)];
  else             v = enc[(size_t)bs * NH + (c - 48)];
  x[idx] = v;
}

// ---------------------------------------------------------------------------
// MERGED 2-layer persistent LSTM (r20 core) with ONE change: the L0 xg
// prefetch is COALESCED -- thread (bp, g) of the first 128 loads one float4
// (4 consecutive j-columns of its gate row; 128 x 16B requests instead of
// 512 x 4B scattered dwords) into a 2.5KB LDS buffer at epoch top (latency
// hides under h staging); L0 pointwise reads its 4 scalars from LDS after
// the gsp sync.  Everything else byte-identical to r20.
// ---------------------------------------------------------------------------
__global__ __launch_bounds__(LTHR)
__attribute__((amdgpu_waves_per_eu(2, 2)))
void lstm_merged(
    const float* __restrict__ xg0,    // [64*32][3072] layer-0 gates (biases folded)
    const float* __restrict__ Whh0,   // [3072][768]
    const unsigned* __restrict__ Wih1pk, // [3072][768] packed hi|lo
    const float* __restrict__ Whh1,   // [3072][768]
    const float* __restrict__ bih1,   // [3072]
    const float* __restrict__ bhh1,   // [3072]
    const unsigned short* __restrict__ hzero, // [32][768] bf16 zeros
    unsigned short* h0,               // [2048][768] bf16, row = t*32+b
    unsigned short* h1,               // [2048][768] bf16
    unsigned* flags) {                // 192 slots at stride 4 u32, zeroed
  extern __shared__ __align__(16) unsigned short smem_us[];
  unsigned short* pA  = smem_us;                 // [32][HP2] bf16(h0)
  unsigned short* pB  = smem_us + 32 * HP2;      // [32][HP2] bf16(h1)
  float*          gsp = (float*)(smem_us + 2 * 32 * HP2);  // [8][16][33]
  float*          xbuf = gsp + 8 * 528;          // [32][20] xg prefetch

  const int tid  = threadIdx.x;
  const int lane = tid & 63;
  const int wid  = tid >> 6;          // 0..7
  const bool wL1 = (wid >= 4);        // waves 4-7 compute layer-1 products
  const int kh   = wid & 3;           // K-quarter (k = kh*192 .. +192)
  const int lm   = lane & 15;
  const int lk   = lane >> 4;
  const int lblk = blockIdx.x;

  // resident Whh frags (L0 or L1 depending on wave -- same registers)
  const int grow = (lm >> 2) * NH + lblk * 4 + (lm & 3);  // gate-row (M=16)
  const float* WhhP = wL1 ? Whh1 : Whh0;
  bf16x8 whi[6], wlo[6];
  #pragma unroll
  for (int s6 = 0; s6 < 6; ++s6) {
    const float* wp = WhhP + (size_t)grow * NH + kh * 192 + s6 * 32 + lk * 8;
    float4 a = *(const float4*)wp;
    float4 b = *(const float4*)(wp + 4);
    float vv[8] = {a.x, a.y, a.z, a.w, b.x, b.y, b.z, b.w};
    #pragma unroll
    for (int i = 0; i < 8; ++i) {
      unsigned short h, l;
      split_bf16(vv[i], h, l);
      whi[s6][i] = (short)h;
      wlo[s6][i] = (short)l;
    }
  }

  // pointwise (tid<256): jp = tid>>5 in 0..7; jp<4 -> L0 cell, else L1
  const int jp = tid >> 5;
  const int bp = tid & 31;
  const bool pwL1 = (jp >= 4);
  const int jloc = jp & 3;
  float c_reg = 0.f;
  float bi = 0.f, bf_ = 0.f, bg = 0.f, bo = 0.f;
  if (tid < 256 && pwL1) {
    const int jj = lblk * 4 + jloc;
    bi  = bih1[0 * NH + jj] + bhh1[0 * NH + jj];
    bf_ = bih1[1 * NH + jj] + bhh1[1 * NH + jj];
    bg  = bih1[2 * NH + jj] + bhh1[2 * NH + jj];
    bo  = bih1[3 * NH + jj] + bhh1[3 * NH + jj];
  }
  const int sb  = tid >> 4;          // staging batch 0..31
  const int sch = tid & 15;          // staging chunk

  for (int e = 0; e <= NS; ++e) {
    const unsigned short* h0r = (e == 0) ? hzero : h0 + (size_t)(e - 1) * NB * NH;
    const unsigned short* h1r = (e <= 1) ? hzero : h1 + (size_t)(e - 2) * NB * NH;
    // ---- coalesced xg prefetch: thread (bq, gq) loads one float4 ----
    if (tid < 128 && e < NS) {
      const int bq = tid & 31, gq = tid >> 5;
      float4 xv = *(const float4*)(xg0 + (size_t)(e * NB + bq) * G4 +
                                   gq * NH + lblk * 4);
      *(float4*)(&xbuf[bq * 20 + gq * 4]) = xv;
    }
    // ---- stage BOTH planes at epoch top: LLC round-trips overlap ----
    stage_hi(h0r, pA, sb, sch);
    stage_hi(h1r, pB, sb, sch);
    __syncthreads();
    f32x4 acc0 = {0.f, 0.f, 0.f, 0.f};
    f32x4 acc1 = {0.f, 0.f, 0.f, 0.f};
    if (!wL1) {
      // L0: gates = Whh0 . h0(e-1)   (2 products: weight hi + weight lo)
      #pragma unroll
      for (int s6 = 0; s6 < 6; ++s6) {
        const int kb = kh * 192 + s6 * 32 + lk * 8;
        bf16x8 b0 = *(bf16x8*)(&pA[lm * HP2 + kb]);
        bf16x8 b1 = *(bf16x8*)(&pA[(16 + lm) * HP2 + kb]);
        acc0 = __builtin_amdgcn_mfma_f32_16x16x32_bf16(whi[s6], b0, acc0, 0, 0, 0);
        acc0 = __builtin_amdgcn_mfma_f32_16x16x32_bf16(wlo[s6], b0, acc0, 0, 0, 0);
        acc1 = __builtin_amdgcn_mfma_f32_16x16x32_bf16(whi[s6], b1, acc1, 0, 0, 0);
        acc1 = __builtin_amdgcn_mfma_f32_16x16x32_bf16(wlo[s6], b1, acc1, 0, 0, 0);
      }
    } else {
      // L1 phase A: acc = Wih1 . h0(e-1)  (packed u-frags, L2-hot)
      #pragma unroll
      for (int s6 = 0; s6 < 6; ++s6) {
        const unsigned* up = Wih1pk + (size_t)grow * NH + kh * 192 + s6 * 32 + lk * 8;
        uint4 ua = *(const uint4*)up;
        uint4 ub = *(const uint4*)(up + 4);
        bf16x8 uh, ul;
        unpack8(ua, ub, uh, ul);
        const int kb = kh * 192 + s6 * 32 + lk * 8;
        bf16x8 b0 = *(bf16x8*)(&pA[lm * HP2 + kb]);
        bf16x8 b1 = *(bf16x8*)(&pA[(16 + lm) * HP2 + kb]);
        acc0 = __builtin_amdgcn_mfma_f32_16x16x32_bf16(uh, b0, acc0, 0, 0, 0);
        acc0 = __builtin_amdgcn_mfma_f32_16x16x32_bf16(ul, b0, acc0, 0, 0, 0);
        acc1 = __builtin_amdgcn_mfma_f32_16x16x32_bf16(uh, b1, acc1, 0, 0, 0);
        acc1 = __builtin_amdgcn_mfma_f32_16x16x32_bf16(ul, b1, acc1, 0, 0, 0);
      }
      // L1 phase B: acc += Whh1 . h1(e-2)  (resident frags, plane B)
      #pragma unroll
      for (int s6 = 0; s6 < 6; ++s6) {
        const int kb = kh * 192 + s6 * 32 + lk * 8;
        bf16x8 b0 = *(bf16x8*)(&pB[lm * HP2 + kb]);
        bf16x8 b1 = *(bf16x8*)(&pB[(16 + lm) * HP2 + kb]);
        acc0 = __builtin_amdgcn_mfma_f32_16x16x32_bf16(whi[s6], b0, acc0, 0, 0, 0);
        acc0 = __builtin_amdgcn_mfma_f32_16x16x32_bf16(wlo[s6], b0, acc0, 0, 0, 0);
        acc1 = __builtin_amdgcn_mfma_f32_16x16x32_bf16(whi[s6], b1, acc1, 0, 0, 0);
        acc1 = __builtin_amdgcn_mfma_f32_16x16x32_bf16(wlo[s6], b1, acc1, 0, 0, 0);
      }
    }
    #pragma unroll
    for (int r4 = 0; r4 < 4; ++r4) {
      gsp[wid * 528 + (lk * 4 + r4) * 33 + lm]      = acc0[r4];
      gsp[wid * 528 + (lk * 4 + r4) * 33 + 16 + lm] = acc1[r4];
    }
    __syncthreads();
    // ---- pointwise for both layers ----
    if (tid < 256) {
      if (!pwL1) {
        if (e < NS) {
          float sum[4];
          #pragma unroll
          for (int g = 0; g < 4; ++g) {
            const int row = g * 4 + jloc;
            sum[g] = gsp[0 * 528 + row * 33 + bp] + gsp[1 * 528 + row * 33 + bp] +
                     gsp[2 * 528 + row * 33 + bp] + gsp[3 * 528 + row * 33 + bp];
          }
          const float xv0 = xbuf[bp * 20 + 0 * 4 + jloc];
          const float xv1 = xbuf[bp * 20 + 1 * 4 + jloc];
          const float xv2 = xbuf[bp * 20 + 2 * 4 + jloc];
          const float xv3 = xbuf[bp * 20 + 3 * 4 + jloc];
          const float si = 1.f / (1.f + expf(-(sum[0] + xv0)));
          const float sf = 1.f / (1.f + expf(-(sum[1] + xv1)));
          const float so = 1.f / (1.f + expf(-(sum[3] + xv3)));
          c_reg = sf * c_reg + si * tanhf(sum[2] + xv2);
          const float hnew = so * tanhf(c_reg);
          coh_store_u16(&h0[(size_t)(e * NB + bp) * NH + lblk * 4 + jloc],
                        rne_bf16(hnew));
        }
      } else {
        if (e >= 1) {
          const int t = e - 1;
          float sum[4];
          #pragma unroll
          for (int g = 0; g < 4; ++g) {
            const int row = g * 4 + jloc;
            sum[g] = gsp[4 * 528 + row * 33 + bp] + gsp[5 * 528 + row * 33 + bp] +
                     gsp[6 * 528 + row * 33 + bp] + gsp[7 * 528 + row * 33 + bp];
          }
          const float si = 1.f / (1.f + expf(-(sum[0] + bi)));
          const float sf = 1.f / (1.f + expf(-(sum[1] + bf_)));
          const float so = 1.f / (1.f + expf(-(sum[3] + bo)));
          c_reg = sf * c_reg + si * tanhf(sum[2] + bg);
          const float hnew = so * tanhf(c_reg);
          coh_store_u16(&h1[(size_t)(t * NB + bp) * NH + lblk * 4 + jloc],
                        rne_bf16(hnew));
        }
      }
    }
    // ---- flag-array grid barrier (epochs 0..63; epoch 64 ends kernel) ----
    if (e < NS) {
      __syncthreads();                 // all waves' h stores issued
      if (tid == 0) {
        asm volatile("s_waitcnt vmcnt(0)" ::: "memory");
        __hip_atomic_store(&flags[(unsigned)blockIdx.x * 4], (unsigned)(e + 1),
                           __ATOMIC_RELAXED, __HIP_MEMORY_SCOPE_AGENT);
      }
      if (tid < FBLK) {
        while (__hip_atomic_load(&flags[(unsigned)tid * 4], __ATOMIC_RELAXED,
                                 __HIP_MEMORY_SCOPE_AGENT) < (unsigned)(e + 1))
          __builtin_amdgcn_s_sleep(1);
      }
      __syncthreads();
    }
  }
}

// ---------------------------------------------------------------------------
// preds[b*24+s] = dot(bf16(h1[s*32+b]), Wout) + bout
// ---------------------------------------------------------------------------
__global__ __launch_bounds__(64) void head_kernel(
    const unsigned short* __restrict__ h1, const float* __restrict__ Wout,
    const float* __restrict__ bout, float* __restrict__ preds) {
  const int o = blockIdx.x;
  const int b = o / HOR_, s = o % HOR_;
  const int l = threadIdx.x;
  const unsigned short* h = h1 + (size_t)(s * NB + b) * NH;
  float acc = 0.f;
  #pragma unroll
  for (int k = l; k < NH; k += 64) {
    const float v = __uint_as_float(((unsigned)h[k]) << 16);
    acc += v * Wout[k];
  }
  #pragma unroll
  for (int m = 32; m; m >>= 1) acc += __shfl_xor(acc, m);
  if (l == 0) preds[o] = acc + bout[0];
}

// ---------------------------------------------------------------------------
extern "C" void kernel_launch(void* const* d_in, const int* in_sizes, int n_in,
                              void* d_out, int out_size, void* d_ws, size_t ws_size,
                              hipStream_t stream) {
  const float* z    = (const float*)d_in[0];
  const float* cond = (const float*)d_in[1];
  const float* encs = (const float*)d_in[2];
  const float* W1   = (const float*)d_in[4];
  const float* b1   = (const float*)d_in[5];
  const float* W2   = (const float*)d_in[6];
  const float* b2   = (const float*)d_in[7];
  const float* Wih0 = (const float*)d_in[8];
  const float* Whh0 = (const float*)d_in[9];
  const float* bih0 = (const float*)d_in[10];
  const float* bhh0 = (const float*)d_in[11];
  const float* Wih1 = (const float*)d_in[12];
  const float* Whh1 = (const float*)d_in[13];
  const float* bih1 = (const float*)d_in[14];
  const float* bhh1 = (const float*)d_in[15];
  const float* Wout = (const float*)d_in[16];
  const float* bout = (const float*)d_in[17];

  float* out     = (float*)d_out;
  float* preds   = out;
  float* enc_out = out + NB * HOR_;

  float* ws    = (float*)d_ws;
  float* xb    = ws + OFF_X;
  float* mean  = ws + OFF_MEAN;
  float* tmp   = ws + OFF_TMP;
  unsigned* wih1pk = (unsigned*)(ws + OFF_WPK);
  unsigned short* h0 = (unsigned short*)(ws + OFF_H0PK);
  unsigned short* h1 = (unsigned short*)(ws + OFF_H1PK);
  float* xg    = ws + OFF_XG;
  unsigned short* hzero = (unsigned short*)(ws + OFF_HZERO);
  unsigned* flags = (unsigned*)(ws + OFF_FLG);

  // allow >64KB dynamic LDS for the persistent kernel
  (void)hipFuncSetAttribute(reinterpret_cast<const void*>(lstm_merged),
                            hipFuncAttributeMaxDynamicSharedMemorySize,
                            160 * 1024);

  // 1. segment mean (filter and mean are linear and commute -> pool first)
  seg_mean_kernel<<<NSEG_, 192, 0, stream>>>(encs, mean);
  // 2. encoded = (mean @ W1^T + b1) @ W2^T + b2 -> straight into d_out (MFMA)
  gemm_mfma_nt<<<dim3(NH / 64, NSEG_ / 64), 256, 0, stream>>>(
      mean, W1, b1, nullptr, tmp, NSEG_, NH, NH);
  gemm_mfma_nt<<<dim3(NH / 64, NSEG_ / 64), 256, 0, stream>>>(
      tmp, W2, b2, nullptr, enc_out, NSEG_, NH, NH);
  // 3. x = concat(z, cond, encoded); pack Wih1 (mean/tmp region now dead)
  build_x_kernel<<<(NSEG_ * NIN) / 256, 256, 0, stream>>>(z, cond, enc_out, xb);
  pack_w_kernel<<<(G4 * NH / 4 + 255) / 256, 256, 0, stream>>>(
      Wih1, wih1pk, G4 * NH / 4);
  // 4. layer-0 input gates (biases folded in), K=816 (guarded chunks)
  gemm_mfma_nt<<<dim3(G4 / 64, NSEG_ / 64), 256, 0, stream>>>(
      xb, Wih0, bih0, bhh0, xg, NSEG_, G4, NIN);
  // 5. merged, pipelined 2-layer recurrence (layer-1 xg GEMM folded in)
  hipMemsetAsync(hzero, 0, (size_t)(SZ_HZERO + 1024) * sizeof(float), stream);
  lstm_merged<<<FBLK, LTHR, SMEM_BYTES, stream>>>(
      xg, Whh0, wih1pk, Whh1, bih1, bhh1, hzero, h0, h1, flags);
  // 6. head
  head_kernel<<<NB * HOR_, 64, 0, stream>>>(h1, Wout, bout, preds);
}